// Round 1
// baseline (1150.511 us; speedup 1.0000x reference)
//
#include <hip/hip_runtime.h>

#define D 128  // D_IN == D_OUT == 128

__global__ void zero_kernel(float4* __restrict__ out, int n4) {
    int i = blockIdx.x * blockDim.x + threadIdx.x;
    int stride = gridDim.x * blockDim.x;
    float4 z = make_float4(0.f, 0.f, 0.f, 0.f);
    for (; i < n4; i += stride) out[i] = z;
}

// support[N,128] = embeds[N,128] @ W[128,128]  (fp32 vector ALU)
__global__ __launch_bounds__(256) void gemm_kernel(const float* __restrict__ embeds,
                                                   const float* __restrict__ W,
                                                   float* __restrict__ support, int N) {
    __shared__ float wLds[D * D];      // 64 KB
    __shared__ float eLds[8][D];       // 4 KB
    const int t = threadIdx.x;

    // Cooperative load of W into LDS (vectorized)
    {
        const float4* w4 = (const float4*)W;
        float4* wl4 = (float4*)wLds;
        #pragma unroll
        for (int i = t; i < D * D / 4; i += 256) wl4[i] = w4[i];
    }
    __syncthreads();

    const int rl = t >> 5;          // row slot 0..7
    const int c4 = (t & 31) << 2;   // col offset (float4 granularity)
    const int ntiles = (N + 7) >> 3;

    for (int tile = blockIdx.x; tile < ntiles; tile += gridDim.x) {
        const int row0 = tile << 3;
        // stage up to 8 rows of embeds
        {
            const float4* e4 = (const float4*)(embeds + (size_t)row0 * D);
            float4* el4 = (float4*)&eLds[0][0];
            const int nf4 = (min(8, N - row0)) * (D / 4);
            if (t < nf4) el4[t] = e4[t];
        }
        __syncthreads();

        const int row = row0 + rl;
        if (row < N) {
            float4 acc = make_float4(0.f, 0.f, 0.f, 0.f);
            #pragma unroll 16
            for (int k = 0; k < D; ++k) {
                const float e = eLds[rl][k];
                const float4 w = *(const float4*)&wLds[k * D + c4];
                acc.x += e * w.x;
                acc.y += e * w.y;
                acc.z += e * w.z;
                acc.w += e * w.w;
            }
            *(float4*)&support[(size_t)row * D + c4] = acc;
        }
        __syncthreads();
    }
}

// out[dst[e]] += vals[e] * support[src[e]]  — 32 threads per edge, 4 cols each
__global__ __launch_bounds__(256) void scatter_kernel(const float* __restrict__ support,
                                                      const int* __restrict__ dst,
                                                      const int* __restrict__ src,
                                                      const float* __restrict__ vals,
                                                      float* __restrict__ out, int E) {
    const int tid = blockIdx.x * blockDim.x + threadIdx.x;
    const int e = tid >> 5;
    if (e >= E) return;
    const int c4 = (tid & 31) << 2;

    const int s = src[e];
    const int d = dst[e];
    const float v = vals[e];

    const float4 m = *(const float4*)&support[(size_t)s * D + c4];
    float* o = &out[(size_t)d * D + c4];
    atomicAdd(o + 0, v * m.x);
    atomicAdd(o + 1, v * m.y);
    atomicAdd(o + 2, v * m.z);
    atomicAdd(o + 3, v * m.w);
}

extern "C" void kernel_launch(void* const* d_in, const int* in_sizes, int n_in,
                              void* d_out, int out_size, void* d_ws, size_t ws_size,
                              hipStream_t stream) {
    const float* embeds = (const float*)d_in[0];
    const float* W      = (const float*)d_in[1];
    const int*   eidx   = (const int*)d_in[2];
    const float* vals   = (const float*)d_in[3];

    const int N = in_sizes[0] / D;   // 100000
    const int E = in_sizes[3];       // 625000
    const int* dstp = eidx;          // edge_index[0]
    const int* srcp = eidx + E;      // edge_index[1]

    float* out = (float*)d_out;
    float* support = (float*)d_ws;   // N*128 floats = 51.2 MB scratch

    // 1) zero output (atomics accumulate into it)
    zero_kernel<<<2048, 256, 0, stream>>>((float4*)out, out_size / 4);

    // 2) support = embeds @ W
    gemm_kernel<<<2048, 256, 0, stream>>>(embeds, W, support, N);

    // 3) scatter-add messages
    const long long nthreads = (long long)E * 32;
    const int blocks = (int)((nthreads + 255) / 256);
    scatter_kernel<<<blocks, 256, 0, stream>>>(support, dstp, srcp, vals, out, E);
}

// Round 2
// 241.319 us; speedup vs baseline: 4.7676x; 4.7676x over previous
//
#include <hip/hip_runtime.h>

#define D 128  // D_IN == D_OUT == 128

// ---------------- utility ----------------

__global__ void zero_int_kernel(int* __restrict__ p, int n) {
    int i = blockIdx.x * blockDim.x + threadIdx.x;
    int stride = gridDim.x * blockDim.x;
    for (; i < n; i += stride) p[i] = 0;
}

__global__ void zero_f4_kernel(float4* __restrict__ out, int n4) {
    int i = blockIdx.x * blockDim.x + threadIdx.x;
    int stride = gridDim.x * blockDim.x;
    float4 z = make_float4(0.f, 0.f, 0.f, 0.f);
    for (; i < n4; i += stride) out[i] = z;
}

// ---------------- GEMM: support = embeds @ W ----------------

__global__ __launch_bounds__(256) void gemm_kernel(const float* __restrict__ embeds,
                                                   const float* __restrict__ W,
                                                   float* __restrict__ support, int N) {
    __shared__ float wLds[D * D];      // 64 KB
    __shared__ float eLds[8][D];       // 4 KB
    const int t = threadIdx.x;

    {
        const float4* w4 = (const float4*)W;
        float4* wl4 = (float4*)wLds;
        #pragma unroll
        for (int i = t; i < D * D / 4; i += 256) wl4[i] = w4[i];
    }
    __syncthreads();

    const int rl = t >> 5;          // row slot 0..7
    const int c4 = (t & 31) << 2;   // col offset (float4 granularity)
    const int ntiles = (N + 7) >> 3;

    for (int tile = blockIdx.x; tile < ntiles; tile += gridDim.x) {
        const int row0 = tile << 3;
        {
            const float4* e4 = (const float4*)(embeds + (size_t)row0 * D);
            float4* el4 = (float4*)&eLds[0][0];
            const int nf4 = (min(8, N - row0)) * (D / 4);
            if (t < nf4) el4[t] = e4[t];
        }
        __syncthreads();

        const int row = row0 + rl;
        if (row < N) {
            float4 acc = make_float4(0.f, 0.f, 0.f, 0.f);
            #pragma unroll 16
            for (int k = 0; k < D; ++k) {
                const float e = eLds[rl][k];
                const float4 w = *(const float4*)&wLds[k * D + c4];
                acc.x += e * w.x;
                acc.y += e * w.y;
                acc.z += e * w.z;
                acc.w += e * w.w;
            }
            *(float4*)&support[(size_t)row * D + c4] = acc;
        }
        __syncthreads();
    }
}

// ---------------- CSR build ----------------

__global__ void hist_kernel(const int* __restrict__ dst, int* __restrict__ cnt, int E) {
    int e = blockIdx.x * blockDim.x + threadIdx.x;
    int stride = gridDim.x * blockDim.x;
    for (; e < E; e += stride) atomicAdd(&cnt[dst[e]], 1);
}

// per-block sums of 1024-element chunks
__global__ __launch_bounds__(256) void scan_reduce(const int* __restrict__ cnt,
                                                   int* __restrict__ partials, int N) {
    __shared__ int l[256];
    const int b = blockIdx.x, t = threadIdx.x;
    const int base = b * 1024 + t * 4;
    int s = 0;
    #pragma unroll
    for (int j = 0; j < 4; ++j) {
        int i = base + j;
        s += (i < N) ? cnt[i] : 0;
    }
    l[t] = s;
    __syncthreads();
    for (int off = 128; off > 0; off >>= 1) {
        if (t < off) l[t] += l[t + off];
        __syncthreads();
    }
    if (t == 0) partials[b] = l[0];
}

// exclusive scan of block partials (nblk <= 128), single block
__global__ __launch_bounds__(128) void scan_partials(int* __restrict__ partials, int nblk) {
    __shared__ int l[128];
    const int t = threadIdx.x;
    const int v = (t < nblk) ? partials[t] : 0;
    l[t] = v;
    __syncthreads();
    for (int off = 1; off < 128; off <<= 1) {
        int x = (t >= off) ? l[t - off] : 0;
        __syncthreads();
        l[t] += x;
        __syncthreads();
    }
    if (t < nblk) partials[t] = l[t] - v;  // exclusive
}

// per-chunk exclusive scan + add base; writes offsets and cursor copy
__global__ __launch_bounds__(256) void scan_final(const int* __restrict__ cnt,
                                                  const int* __restrict__ partials,
                                                  int* __restrict__ offsets,
                                                  int* __restrict__ cursor, int N, int E) {
    __shared__ int l[256];
    const int b = blockIdx.x, t = threadIdx.x;
    const int base = b * 1024 + t * 4;
    int v[4];
    int s = 0;
    #pragma unroll
    for (int j = 0; j < 4; ++j) {
        int i = base + j;
        v[j] = (i < N) ? cnt[i] : 0;
        s += v[j];
    }
    l[t] = s;
    __syncthreads();
    for (int off = 1; off < 256; off <<= 1) {
        int x = (t >= off) ? l[t - off] : 0;
        __syncthreads();
        l[t] += x;
        __syncthreads();
    }
    int run = l[t] - s + partials[b];
    #pragma unroll
    for (int j = 0; j < 4; ++j) {
        int i = base + j;
        if (i < N) { offsets[i] = run; cursor[i] = run; }
        run += v[j];
    }
    if (b == 0 && t == 0) offsets[N] = E;
}

// scatter (src, val) into dst-sorted payload arrays
__global__ void fill_kernel(const int* __restrict__ dst, const int* __restrict__ src,
                            const float* __restrict__ vals, int* __restrict__ cursor,
                            int* __restrict__ src_s, float* __restrict__ val_s, int E) {
    int e = blockIdx.x * blockDim.x + threadIdx.x;
    int stride = gridDim.x * blockDim.x;
    for (; e < E; e += stride) {
        int d = dst[e];
        int pos = atomicAdd(&cursor[d], 1);
        src_s[pos] = src[e];
        val_s[pos] = vals[e];
    }
}

// ---------------- gather-accumulate: one wave per dst node ----------------

__global__ __launch_bounds__(256) void gather_kernel(const float* __restrict__ support,
                                                     const int* __restrict__ offsets,
                                                     const int* __restrict__ src_s,
                                                     const float* __restrict__ val_s,
                                                     float* __restrict__ out, int N) {
    const int wid = (blockIdx.x * 256 + threadIdx.x) >> 6;  // wave id = node id
    const int lane = threadIdx.x & 63;
    if (wid >= N) return;

    const int beg = offsets[wid];
    const int end = offsets[wid + 1];
    const int c = lane * 2;

    float2 acc = make_float2(0.f, 0.f);
    for (int i = beg; i < end; ++i) {
        const int s = src_s[i];
        const float v = val_s[i];
        const float2 m = *(const float2*)&support[(size_t)s * D + c];
        acc.x += v * m.x;
        acc.y += v * m.y;
    }
    *(float2*)&out[(size_t)wid * D + c] = acc;
}

// ---------------- fallback: atomic scatter (if ws too small) ----------------

__global__ __launch_bounds__(256) void scatter_kernel(const float* __restrict__ support,
                                                      const int* __restrict__ dst,
                                                      const int* __restrict__ src,
                                                      const float* __restrict__ vals,
                                                      float* __restrict__ out, int E) {
    const int tid = blockIdx.x * blockDim.x + threadIdx.x;
    const int e = tid >> 5;
    if (e >= E) return;
    const int c4 = (tid & 31) << 2;

    const int s = src[e];
    const int d = dst[e];
    const float v = vals[e];

    const float4 m = *(const float4*)&support[(size_t)s * D + c4];
    float* o = &out[(size_t)d * D + c4];
    atomicAdd(o + 0, v * m.x);
    atomicAdd(o + 1, v * m.y);
    atomicAdd(o + 2, v * m.z);
    atomicAdd(o + 3, v * m.w);
}

// ---------------- launch ----------------

extern "C" void kernel_launch(void* const* d_in, const int* in_sizes, int n_in,
                              void* d_out, int out_size, void* d_ws, size_t ws_size,
                              hipStream_t stream) {
    const float* embeds = (const float*)d_in[0];
    const float* W      = (const float*)d_in[1];
    const int*   eidx   = (const int*)d_in[2];
    const float* vals   = (const float*)d_in[3];

    const int N = in_sizes[0] / D;   // 100000
    const int E = in_sizes[3];       // 625000
    const int* dstp = eidx;          // edge_index[0]
    const int* srcp = eidx + E;      // edge_index[1]

    float* out = (float*)d_out;

    // workspace layout
    char* p = (char*)d_ws;
    float* support = (float*)p;           p += (size_t)N * D * 4;   // 51.2 MB
    int* cnt       = (int*)p;             p += (size_t)N * 4;
    int* offsets   = (int*)p;             p += (size_t)(N + 1) * 4;
    int* cursor    = (int*)p;             p += (size_t)N * 4;
    int* partials  = (int*)p;             p += 4096;
    int* src_s     = (int*)p;             p += (size_t)E * 4;
    float* val_s   = (float*)p;           p += (size_t)E * 4;
    const size_t needed = (size_t)(p - (char*)d_ws);

    // 1) support = embeds @ W
    gemm_kernel<<<2048, 256, 0, stream>>>(embeds, W, support, N);

    if (ws_size >= needed) {
        // --- CSR path: no output atomics ---
        const int nblk = (N + 1023) / 1024;   // 98 for N=100000 (must be <=128)
        zero_int_kernel<<<128, 256, 0, stream>>>(cnt, N);
        hist_kernel<<<2048, 256, 0, stream>>>(dstp, cnt, E);
        scan_reduce<<<nblk, 256, 0, stream>>>(cnt, partials, N);
        scan_partials<<<1, 128, 0, stream>>>(partials, nblk);
        scan_final<<<nblk, 256, 0, stream>>>(cnt, partials, offsets, cursor, N, E);
        fill_kernel<<<2048, 256, 0, stream>>>(dstp, srcp, vals, cursor, src_s, val_s, E);
        gather_kernel<<<(N + 3) / 4, 256, 0, stream>>>(support, offsets, src_s, val_s, out, N);
    } else {
        // --- fallback: atomic scatter ---
        zero_f4_kernel<<<2048, 256, 0, stream>>>((float4*)out, out_size / 4);
        const long long nthreads = (long long)E * 32;
        const int blocks = (int)((nthreads + 255) / 256);
        scatter_kernel<<<blocks, 256, 0, stream>>>(support, dstp, srcp, vals, out, E);
    }
}

// Round 3
// 179.206 us; speedup vs baseline: 6.4201x; 1.3466x over previous
//
#include <hip/hip_runtime.h>

#define D 128  // D_IN == D_OUT == 128

typedef __attribute__((ext_vector_type(8))) short short8;
typedef __attribute__((ext_vector_type(4))) float f32x4;

__device__ inline ushort f2bf(float f) {   // fp32 -> bf16 RNE
    uint u = __float_as_uint(f);
    uint r = (u + 0x7FFFu + ((u >> 16) & 1u)) >> 16;
    return (ushort)r;
}

// ---------------- utility ----------------

__global__ void zero_int_kernel(int* __restrict__ p, int n) {
    int i = blockIdx.x * blockDim.x + threadIdx.x;
    int stride = gridDim.x * blockDim.x;
    for (; i < n; i += stride) p[i] = 0;
}

__global__ void zero_f4_kernel(float4* __restrict__ out, int n4) {
    int i = blockIdx.x * blockDim.x + threadIdx.x;
    int stride = gridDim.x * blockDim.x;
    float4 z = make_float4(0.f, 0.f, 0.f, 0.f);
    for (; i < n4; i += stride) out[i] = z;
}

// W[128][128] fp32 -> W^T[128][128] bf16
__global__ __launch_bounds__(256) void convert_w_kernel(const float* __restrict__ W,
                                                        ushort* __restrict__ wT) {
    int t = blockIdx.x * 256 + threadIdx.x;
    if (t >= D * D) return;
    int r = t >> 7, c = t & 127;
    wT[c * D + r] = f2bf(W[t]);
}

// ---------------- GEMM: support_bf16 = bf16(embeds @ W), via MFMA ----------------

__global__ __launch_bounds__(256) void gemm_mfma(const float* __restrict__ embeds,
                                                 const ushort* __restrict__ wT,
                                                 ushort* __restrict__ support, int N) {
    __shared__ ushort aLds[64 * D];    // 16 KB, XOR-swizzled rows
    __shared__ ushort bLds[D * D];     // 32 KB, XOR-swizzled rows (stores W^T: [n][k])
    const int t = threadIdx.x;
    const int w = t >> 6;        // wave 0..3
    const int l = t & 63;

    // stage W^T (block-invariant): 2048 x 16B chunks
    #pragma unroll
    for (int c = 0; c < 8; ++c) {
        int chunk = c * 256 + t;
        int byteoff = chunk * 16;
        int n = byteoff >> 8;                       // row (n) of wT
        int dstoff = byteoff ^ ((n & 7) << 4);
        *(float4*)((char*)bLds + dstoff) = *(const float4*)((const char*)wT + byteoff);
    }

    const int ntiles = (N + 63) >> 6;
    const int kgrp = l >> 4;             // 0..3
    const int lan15 = l & 15;

    for (int tile = blockIdx.x; tile < ntiles; tile += gridDim.x) {
        const int row0 = tile << 6;
        __syncthreads();   // prior compute done (and W staged, first iter)

        // stage A tile: 64 rows x 128 cols fp32 -> bf16; 1024 chunks of 8 floats
        #pragma unroll
        for (int c = 0; c < 4; ++c) {
            int chunk = c * 256 + t;
            int rl = chunk >> 4;               // local row
            int cf = (chunk & 15) * 8;         // col (floats)
            int grow = row0 + rl;
            short8 v;
            if (grow < N) {
                const float* src = embeds + (size_t)grow * D + cf;
                float4 f0 = *(const float4*)src;
                float4 f1 = *(const float4*)(src + 4);
                v[0] = (short)f2bf(f0.x); v[1] = (short)f2bf(f0.y);
                v[2] = (short)f2bf(f0.z); v[3] = (short)f2bf(f0.w);
                v[4] = (short)f2bf(f1.x); v[5] = (short)f2bf(f1.y);
                v[6] = (short)f2bf(f1.z); v[7] = (short)f2bf(f1.w);
            } else {
                v = (short8)0;
            }
            int byteoff = rl * 256 + cf * 2;
            int dstoff = byteoff ^ ((rl & 7) << 4);
            *(short8*)((char*)aLds + dstoff) = v;
        }
        __syncthreads();

        // compute: wave w owns local rows w*16..w*16+15, all 128 cols
        f32x4 acc[8];
        #pragma unroll
        for (int ct = 0; ct < 8; ++ct) acc[ct] = (f32x4)0.0f;

        const int arow = w * 16 + lan15;
        #pragma unroll
        for (int ks = 0; ks < 4; ++ks) {
            const int kbyte = ks * 64 + kgrp * 16;
            const int aoff = (arow * 256 + kbyte) ^ ((arow & 7) << 4);
            short8 af = *(const short8*)((const char*)aLds + aoff);
            #pragma unroll
            for (int ct = 0; ct < 8; ++ct) {
                const int n = ct * 16 + lan15;
                const int boff = (n * 256 + kbyte) ^ ((n & 7) << 4);
                short8 bfr = *(const short8*)((const char*)bLds + boff);
                acc[ct] = __builtin_amdgcn_mfma_f32_16x16x32_bf16(af, bfr, acc[ct], 0, 0, 0);
            }
        }

        // store: C/D layout col=lane&15, row=(lane>>4)*4+r
        #pragma unroll
        for (int r = 0; r < 4; ++r) {
            const int grow = row0 + w * 16 + kgrp * 4 + r;
            if (grow < N) {
                #pragma unroll
                for (int ct = 0; ct < 8; ++ct) {
                    support[(size_t)grow * D + ct * 16 + lan15] = f2bf(acc[ct][r]);
                }
            }
        }
    }
}

// ---------------- CSR build ----------------

__global__ void hist_kernel(const int* __restrict__ dst, int* __restrict__ cnt, int E) {
    int e = blockIdx.x * blockDim.x + threadIdx.x;
    int stride = gridDim.x * blockDim.x;
    for (; e < E; e += stride) atomicAdd(&cnt[dst[e]], 1);
}

__global__ __launch_bounds__(256) void scan_reduce(const int* __restrict__ cnt,
                                                   int* __restrict__ partials, int N) {
    __shared__ int l[256];
    const int b = blockIdx.x, t = threadIdx.x;
    const int base = b * 1024 + t * 4;
    int s = 0;
    #pragma unroll
    for (int j = 0; j < 4; ++j) {
        int i = base + j;
        s += (i < N) ? cnt[i] : 0;
    }
    l[t] = s;
    __syncthreads();
    for (int off = 128; off > 0; off >>= 1) {
        if (t < off) l[t] += l[t + off];
        __syncthreads();
    }
    if (t == 0) partials[b] = l[0];
}

__global__ __launch_bounds__(128) void scan_partials(int* __restrict__ partials, int nblk) {
    __shared__ int l[128];
    const int t = threadIdx.x;
    const int v = (t < nblk) ? partials[t] : 0;
    l[t] = v;
    __syncthreads();
    for (int off = 1; off < 128; off <<= 1) {
        int x = (t >= off) ? l[t - off] : 0;
        __syncthreads();
        l[t] += x;
        __syncthreads();
    }
    if (t < nblk) partials[t] = l[t] - v;  // exclusive
}

__global__ __launch_bounds__(256) void scan_final(const int* __restrict__ cnt,
                                                  const int* __restrict__ partials,
                                                  int* __restrict__ offsets,
                                                  int* __restrict__ cursor, int N, int E) {
    __shared__ int l[256];
    const int b = blockIdx.x, t = threadIdx.x;
    const int base = b * 1024 + t * 4;
    int v[4];
    int s = 0;
    #pragma unroll
    for (int j = 0; j < 4; ++j) {
        int i = base + j;
        v[j] = (i < N) ? cnt[i] : 0;
        s += v[j];
    }
    l[t] = s;
    __syncthreads();
    for (int off = 1; off < 256; off <<= 1) {
        int x = (t >= off) ? l[t - off] : 0;
        __syncthreads();
        l[t] += x;
        __syncthreads();
    }
    int run = l[t] - s + partials[b];
    #pragma unroll
    for (int j = 0; j < 4; ++j) {
        int i = base + j;
        if (i < N) { offsets[i] = run; cursor[i] = run; }
        run += v[j];
    }
    if (b == 0 && t == 0) offsets[N] = E;
}

// scatter (src, val) into dst-sorted payload (packed int2: {src, val_bits})
__global__ void fill_kernel(const int* __restrict__ dst, const int* __restrict__ src,
                            const float* __restrict__ vals, int* __restrict__ cursor,
                            int2* __restrict__ pay, int E) {
    int e = blockIdx.x * blockDim.x + threadIdx.x;
    int stride = gridDim.x * blockDim.x;
    for (; e < E; e += stride) {
        int d = dst[e];
        int pos = atomicAdd(&cursor[d], 1);
        pay[pos] = make_int2(src[e], __float_as_int(vals[e]));
    }
}

// ---------------- gather-accumulate: one wave per dst node ----------------

__global__ __launch_bounds__(256) void gather_kernel(const ushort* __restrict__ support,
                                                     const int* __restrict__ offsets,
                                                     const int2* __restrict__ pay,
                                                     float* __restrict__ out, int N) {
    const int wid = (blockIdx.x * 256 + threadIdx.x) >> 6;  // wave id = node id
    const int lane = threadIdx.x & 63;
    if (wid >= N) return;

    const int beg = offsets[wid];
    const int end = offsets[wid + 1];
    const int c = lane * 2;

    float ax = 0.f, ay = 0.f;
    for (int i = beg; i < end; ++i) {
        const int2 p = pay[i];
        const float v = __int_as_float(p.y);
        const uint m = *(const uint*)&support[(size_t)p.x * D + c];  // 2 bf16
        const float mx = __uint_as_float((m & 0xFFFFu) << 16);
        const float my = __uint_as_float(m & 0xFFFF0000u);
        ax += v * mx;
        ay += v * my;
    }
    *(float2*)&out[(size_t)wid * D + c] = make_float2(ax, ay);
}

// ---------------- fallback: atomic scatter (if ws too small) ----------------

__global__ __launch_bounds__(256) void scatter_kernel(const ushort* __restrict__ support,
                                                      const int* __restrict__ dst,
                                                      const int* __restrict__ src,
                                                      const float* __restrict__ vals,
                                                      float* __restrict__ out, int E) {
    const long long tid = (long long)blockIdx.x * blockDim.x + threadIdx.x;
    const int e = (int)(tid >> 6);
    if (e >= E) return;
    const int c = ((int)tid & 63) * 2;

    const int s = src[e];
    const int d = dst[e];
    const float v = vals[e];

    const uint m = *(const uint*)&support[(size_t)s * D + c];
    const float mx = __uint_as_float((m & 0xFFFFu) << 16);
    const float my = __uint_as_float(m & 0xFFFF0000u);
    atomicAdd(&out[(size_t)d * D + c + 0], v * mx);
    atomicAdd(&out[(size_t)d * D + c + 1], v * my);
}

// ---------------- launch ----------------

extern "C" void kernel_launch(void* const* d_in, const int* in_sizes, int n_in,
                              void* d_out, int out_size, void* d_ws, size_t ws_size,
                              hipStream_t stream) {
    const float* embeds = (const float*)d_in[0];
    const float* W      = (const float*)d_in[1];
    const int*   eidx   = (const int*)d_in[2];
    const float* vals   = (const float*)d_in[3];

    const int N = in_sizes[0] / D;   // 100000
    const int E = in_sizes[3];       // 625000
    const int* dstp = eidx;          // edge_index[0]
    const int* srcp = eidx + E;      // edge_index[1]

    float* out = (float*)d_out;

    // workspace layout
    char* p = (char*)d_ws;
    ushort* support = (ushort*)p;      p += (size_t)N * D * 2;    // 25.6 MB bf16
    ushort* wT      = (ushort*)p;      p += (size_t)D * D * 2;    // 32 KB
    int* cnt        = (int*)p;         p += (size_t)N * 4;
    int* offsets    = (int*)p;         p += (size_t)(N + 1) * 4;
    int* cursor     = (int*)p;         p += (size_t)N * 4;
    int* partials   = (int*)p;         p += 4096;
    int2* pay       = (int2*)p;        p += (size_t)E * 8;
    const size_t needed = (size_t)(p - (char*)d_ws);

    // 1) W -> W^T bf16; support = bf16(embeds @ W)
    convert_w_kernel<<<(D * D + 255) / 256, 256, 0, stream>>>(W, wT);
    const int ntiles = (N + 63) / 64;
    gemm_mfma<<<ntiles, 256, 0, stream>>>(embeds, wT, support, N);

    if (ws_size >= needed) {
        // --- CSR path: no output atomics ---
        const int nblk = (N + 1023) / 1024;   // 98 (<=128)
        zero_int_kernel<<<128, 256, 0, stream>>>(cnt, N);
        hist_kernel<<<2048, 256, 0, stream>>>(dstp, cnt, E);
        scan_reduce<<<nblk, 256, 0, stream>>>(cnt, partials, N);
        scan_partials<<<1, 128, 0, stream>>>(partials, nblk);
        scan_final<<<nblk, 256, 0, stream>>>(cnt, partials, offsets, cursor, N, E);
        fill_kernel<<<2048, 256, 0, stream>>>(dstp, srcp, vals, cursor, pay, E);
        gather_kernel<<<(N + 3) / 4, 256, 0, stream>>>(support, offsets, pay, out, N);
    } else {
        // --- fallback: atomic scatter ---
        zero_f4_kernel<<<2048, 256, 0, stream>>>((float4*)out, out_size / 4);
        const long long nthreads = (long long)E * 64;
        const int blocks = (int)((nthreads + 255) / 256);
        scatter_kernel<<<blocks, 256, 0, stream>>>(support, dstp, srcp, vals, out, E);
    }
}

// Round 4
// 145.859 us; speedup vs baseline: 7.8878x; 1.2286x over previous
//
#include <hip/hip_runtime.h>

#define D 128  // D_IN == D_OUT == 128

typedef __attribute__((ext_vector_type(8))) short short8;
typedef __attribute__((ext_vector_type(4))) float f32x4;

__device__ inline ushort f2bf(float f) {   // fp32 -> bf16 RNE
    uint u = __float_as_uint(f);
    uint r = (u + 0x7FFFu + ((u >> 16) & 1u)) >> 16;
    return (ushort)r;
}

// ---------------- utility ----------------

__global__ void zero_int_kernel(int* __restrict__ p, int n) {
    int i = blockIdx.x * blockDim.x + threadIdx.x;
    int stride = gridDim.x * blockDim.x;
    for (; i < n; i += stride) p[i] = 0;
}

__global__ void zero_f4_kernel(float4* __restrict__ out, int n4) {
    int i = blockIdx.x * blockDim.x + threadIdx.x;
    int stride = gridDim.x * blockDim.x;
    float4 z = make_float4(0.f, 0.f, 0.f, 0.f);
    for (; i < n4; i += stride) out[i] = z;
}

// W[128][128] fp32 -> W^T[128][128] bf16
__global__ __launch_bounds__(256) void convert_w_kernel(const float* __restrict__ W,
                                                        ushort* __restrict__ wT) {
    int t = blockIdx.x * 256 + threadIdx.x;
    if (t >= D * D) return;
    int r = t >> 7, c = t & 127;
    wT[c * D + r] = f2bf(W[t]);
}

// ---------------- GEMM: support_bf16 = bf16(embeds @ W), via MFMA ----------------

__global__ __launch_bounds__(256) void gemm_mfma(const float* __restrict__ embeds,
                                                 const ushort* __restrict__ wT,
                                                 ushort* __restrict__ support, int N) {
    __shared__ ushort aLds[64 * D];    // 16 KB, XOR-swizzled rows
    __shared__ ushort bLds[D * D];     // 32 KB, XOR-swizzled rows (stores W^T: [n][k])
    const int t = threadIdx.x;
    const int w = t >> 6;        // wave 0..3
    const int l = t & 63;

    // stage W^T (block-invariant): 2048 x 16B chunks
    #pragma unroll
    for (int c = 0; c < 8; ++c) {
        int chunk = c * 256 + t;
        int byteoff = chunk * 16;
        int n = byteoff >> 8;                       // row (n) of wT
        int dstoff = byteoff ^ ((n & 7) << 4);
        *(float4*)((char*)bLds + dstoff) = *(const float4*)((const char*)wT + byteoff);
    }

    const int ntiles = (N + 63) >> 6;
    const int kgrp = l >> 4;             // 0..3
    const int lan15 = l & 15;

    for (int tile = blockIdx.x; tile < ntiles; tile += gridDim.x) {
        const int row0 = tile << 6;
        __syncthreads();   // prior compute done (and W staged, first iter)

        // stage A tile: 64 rows x 128 cols fp32 -> bf16; 1024 chunks of 8 floats
        #pragma unroll
        for (int c = 0; c < 4; ++c) {
            int chunk = c * 256 + t;
            int rl = chunk >> 4;               // local row
            int cf = (chunk & 15) * 8;         // col (floats)
            int grow = row0 + rl;
            short8 v;
            if (grow < N) {
                const float* src = embeds + (size_t)grow * D + cf;
                float4 f0 = *(const float4*)src;
                float4 f1 = *(const float4*)(src + 4);
                v[0] = (short)f2bf(f0.x); v[1] = (short)f2bf(f0.y);
                v[2] = (short)f2bf(f0.z); v[3] = (short)f2bf(f0.w);
                v[4] = (short)f2bf(f1.x); v[5] = (short)f2bf(f1.y);
                v[6] = (short)f2bf(f1.z); v[7] = (short)f2bf(f1.w);
            } else {
                v = (short8)0;
            }
            int byteoff = rl * 256 + cf * 2;
            int dstoff = byteoff ^ ((rl & 7) << 4);
            *(short8*)((char*)aLds + dstoff) = v;
        }
        __syncthreads();

        // compute: wave w owns local rows w*16..w*16+15, all 128 cols
        f32x4 acc[8];
        #pragma unroll
        for (int ct = 0; ct < 8; ++ct) acc[ct] = (f32x4)0.0f;

        const int arow = w * 16 + lan15;
        #pragma unroll
        for (int ks = 0; ks < 4; ++ks) {
            const int kbyte = ks * 64 + kgrp * 16;
            const int aoff = (arow * 256 + kbyte) ^ ((arow & 7) << 4);
            short8 af = *(const short8*)((const char*)aLds + aoff);
            #pragma unroll
            for (int ct = 0; ct < 8; ++ct) {
                const int n = ct * 16 + lan15;
                const int boff = (n * 256 + kbyte) ^ ((n & 7) << 4);
                short8 bfr = *(const short8*)((const char*)bLds + boff);
                acc[ct] = __builtin_amdgcn_mfma_f32_16x16x32_bf16(af, bfr, acc[ct], 0, 0, 0);
            }
        }

        // store: C/D layout col=lane&15, row=(lane>>4)*4+r
        #pragma unroll
        for (int r = 0; r < 4; ++r) {
            const int grow = row0 + w * 16 + kgrp * 4 + r;
            if (grow < N) {
                #pragma unroll
                for (int ct = 0; ct < 8; ++ct) {
                    support[(size_t)grow * D + ct * 16 + lan15] = f2bf(acc[ct][r]);
                }
            }
        }
    }
}

// ---------------- CSR build ----------------

__global__ void hist_kernel(const int* __restrict__ dst, int* __restrict__ cnt, int E) {
    int e = blockIdx.x * blockDim.x + threadIdx.x;
    int stride = gridDim.x * blockDim.x;
    for (; e < E; e += stride) atomicAdd(&cnt[dst[e]], 1);
}

__global__ __launch_bounds__(256) void scan_reduce(const int* __restrict__ cnt,
                                                   int* __restrict__ partials, int N) {
    __shared__ int l[256];
    const int b = blockIdx.x, t = threadIdx.x;
    const int base = b * 1024 + t * 4;
    int s = 0;
    #pragma unroll
    for (int j = 0; j < 4; ++j) {
        int i = base + j;
        s += (i < N) ? cnt[i] : 0;
    }
    l[t] = s;
    __syncthreads();
    for (int off = 128; off > 0; off >>= 1) {
        if (t < off) l[t] += l[t + off];
        __syncthreads();
    }
    if (t == 0) partials[b] = l[0];
}

__global__ __launch_bounds__(128) void scan_partials(int* __restrict__ partials, int nblk) {
    __shared__ int l[128];
    const int t = threadIdx.x;
    const int v = (t < nblk) ? partials[t] : 0;
    l[t] = v;
    __syncthreads();
    for (int off = 1; off < 128; off <<= 1) {
        int x = (t >= off) ? l[t - off] : 0;
        __syncthreads();
        l[t] += x;
        __syncthreads();
    }
    if (t < nblk) partials[t] = l[t] - v;  // exclusive
}

__global__ __launch_bounds__(256) void scan_final(const int* __restrict__ cnt,
                                                  const int* __restrict__ partials,
                                                  int* __restrict__ offsets,
                                                  int* __restrict__ cursor, int N, int E) {
    __shared__ int l[256];
    const int b = blockIdx.x, t = threadIdx.x;
    const int base = b * 1024 + t * 4;
    int v[4];
    int s = 0;
    #pragma unroll
    for (int j = 0; j < 4; ++j) {
        int i = base + j;
        v[j] = (i < N) ? cnt[i] : 0;
        s += v[j];
    }
    l[t] = s;
    __syncthreads();
    for (int off = 1; off < 256; off <<= 1) {
        int x = (t >= off) ? l[t - off] : 0;
        __syncthreads();
        l[t] += x;
        __syncthreads();
    }
    int run = l[t] - s + partials[b];
    #pragma unroll
    for (int j = 0; j < 4; ++j) {
        int i = base + j;
        if (i < N) { offsets[i] = run; cursor[i] = run; }
        run += v[j];
    }
    if (b == 0 && t == 0) offsets[N] = E;
}

// scatter (src, val) into dst-sorted payload (packed int2: {src, val_bits})
__global__ void fill_kernel(const int* __restrict__ dst, const int* __restrict__ src,
                            const float* __restrict__ vals, int* __restrict__ cursor,
                            int2* __restrict__ pay, int E) {
    int e = blockIdx.x * blockDim.x + threadIdx.x;
    int stride = gridDim.x * blockDim.x;
    for (; e < E; e += stride) {
        int d = dst[e];
        int pos = atomicAdd(&cursor[d], 1);
        pay[pos] = make_int2(src[e], __float_as_int(vals[e]));
    }
}

// ---------------- gather-accumulate: one wave per dst node, 4 edges in flight ----------------

__global__ __launch_bounds__(256) void gather_kernel(const ushort* __restrict__ support,
                                                     const int* __restrict__ offsets,
                                                     const int2* __restrict__ pay,
                                                     float* __restrict__ out, int N) {
    const int wid = (blockIdx.x * 256 + threadIdx.x) >> 6;  // wave id = node id
    const int lane = threadIdx.x & 63;
    if (wid >= N) return;

    const int beg = offsets[wid];
    const int end = offsets[wid + 1];
    const int g  = lane >> 4;    // edge slot 0..3
    const int sl = lane & 15;    // column sublane: cols sl*8 .. sl*8+7

    float acc[8];
    #pragma unroll
    for (int j = 0; j < 8; ++j) acc[j] = 0.f;

    for (int i = beg + g; i < end; i += 4) {
        const int2 p = pay[i];
        const float v = __int_as_float(p.y);
        const uint4 m = *(const uint4*)&support[(size_t)p.x * D + sl * 8];  // 8 bf16
        acc[0] += v * __uint_as_float((m.x & 0xFFFFu) << 16);
        acc[1] += v * __uint_as_float(m.x & 0xFFFF0000u);
        acc[2] += v * __uint_as_float((m.y & 0xFFFFu) << 16);
        acc[3] += v * __uint_as_float(m.y & 0xFFFF0000u);
        acc[4] += v * __uint_as_float((m.z & 0xFFFFu) << 16);
        acc[5] += v * __uint_as_float(m.z & 0xFFFF0000u);
        acc[6] += v * __uint_as_float((m.w & 0xFFFFu) << 16);
        acc[7] += v * __uint_as_float(m.w & 0xFFFF0000u);
    }

    // combine the 4 edge-slot partials (lanes sharing sl): xor 16 then 32
    #pragma unroll
    for (int j = 0; j < 8; ++j) {
        acc[j] += __shfl_xor(acc[j], 16, 64);
        acc[j] += __shfl_xor(acc[j], 32, 64);
    }

    if (g == 0) {
        float* o = &out[(size_t)wid * D + sl * 8];
        *(float4*)o       = make_float4(acc[0], acc[1], acc[2], acc[3]);
        *(float4*)(o + 4) = make_float4(acc[4], acc[5], acc[6], acc[7]);
    }
}

// ---------------- fallback: atomic scatter (if ws too small) ----------------

__global__ __launch_bounds__(256) void scatter_kernel(const ushort* __restrict__ support,
                                                      const int* __restrict__ dst,
                                                      const int* __restrict__ src,
                                                      const float* __restrict__ vals,
                                                      float* __restrict__ out, int E) {
    const long long tid = (long long)blockIdx.x * blockDim.x + threadIdx.x;
    const int e = (int)(tid >> 6);
    if (e >= E) return;
    const int c = ((int)tid & 63) * 2;

    const int s = src[e];
    const int d = dst[e];
    const float v = vals[e];

    const uint m = *(const uint*)&support[(size_t)s * D + c];
    const float mx = __uint_as_float((m & 0xFFFFu) << 16);
    const float my = __uint_as_float(m & 0xFFFF0000u);
    atomicAdd(&out[(size_t)d * D + c + 0], v * mx);
    atomicAdd(&out[(size_t)d * D + c + 1], v * my);
}

// ---------------- launch ----------------

extern "C" void kernel_launch(void* const* d_in, const int* in_sizes, int n_in,
                              void* d_out, int out_size, void* d_ws, size_t ws_size,
                              hipStream_t stream) {
    const float* embeds = (const float*)d_in[0];
    const float* W      = (const float*)d_in[1];
    const int*   eidx   = (const int*)d_in[2];
    const float* vals   = (const float*)d_in[3];

    const int N = in_sizes[0] / D;   // 100000
    const int E = in_sizes[3];       // 625000
    const int* dstp = eidx;          // edge_index[0]
    const int* srcp = eidx + E;      // edge_index[1]

    float* out = (float*)d_out;

    // workspace layout
    char* p = (char*)d_ws;
    ushort* support = (ushort*)p;      p += (size_t)N * D * 2;    // 25.6 MB bf16
    ushort* wT      = (ushort*)p;      p += (size_t)D * D * 2;    // 32 KB
    int* cnt        = (int*)p;         p += (size_t)N * 4;
    int* offsets    = (int*)p;         p += (size_t)(N + 1) * 4;
    int* cursor     = (int*)p;         p += (size_t)N * 4;
    int* partials   = (int*)p;         p += 4096;
    int2* pay       = (int2*)p;        p += (size_t)E * 8;
    const size_t needed = (size_t)(p - (char*)d_ws);

    // 1) W -> W^T bf16; support = bf16(embeds @ W)
    convert_w_kernel<<<(D * D + 255) / 256, 256, 0, stream>>>(W, wT);
    gemm_mfma<<<768, 256, 0, stream>>>(embeds, wT, support, N);

    if (ws_size >= needed) {
        // --- CSR path: no output atomics ---
        const int nblk = (N + 1023) / 1024;   // 98 (<=128)
        zero_int_kernel<<<128, 256, 0, stream>>>(cnt, N);
        hist_kernel<<<2048, 256, 0, stream>>>(dstp, cnt, E);
        scan_reduce<<<nblk, 256, 0, stream>>>(cnt, partials, N);
        scan_partials<<<1, 128, 0, stream>>>(partials, nblk);
        scan_final<<<nblk, 256, 0, stream>>>(cnt, partials, offsets, cursor, N, E);
        fill_kernel<<<2048, 256, 0, stream>>>(dstp, srcp, vals, cursor, pay, E);
        gather_kernel<<<(N + 3) / 4, 256, 0, stream>>>(support, offsets, pay, out, N);
    } else {
        // --- fallback: atomic scatter ---
        zero_f4_kernel<<<2048, 256, 0, stream>>>((float4*)out, out_size / 4);
        const long long nthreads = (long long)E * 64;
        const int blocks = (int)((nthreads + 255) / 256);
        scatter_kernel<<<blocks, 256, 0, stream>>>(support, dstp, srcp, vals, out, E);
    }
}

// Round 5
// 143.885 us; speedup vs baseline: 7.9961x; 1.0137x over previous
//
#include <hip/hip_runtime.h>

#define D 128   // D_IN == D_OUT == 128
#define CB 1024 // nodes per coarse bucket
#define NB_MAX 128

typedef __attribute__((ext_vector_type(8))) short short8;
typedef __attribute__((ext_vector_type(4))) float f32x4;

__device__ inline ushort f2bf(float f) {   // fp32 -> bf16 RNE
    uint u = __float_as_uint(f);
    uint r = (u + 0x7FFFu + ((u >> 16) & 1u)) >> 16;
    return (ushort)r;
}

// ---------------- utility ----------------

__global__ void zero_int_kernel(int* __restrict__ p, int n) {
    int i = blockIdx.x * blockDim.x + threadIdx.x;
    int stride = gridDim.x * blockDim.x;
    for (; i < n; i += stride) p[i] = 0;
}

__global__ void zero_f4_kernel(float4* __restrict__ out, int n4) {
    int i = blockIdx.x * blockDim.x + threadIdx.x;
    int stride = gridDim.x * blockDim.x;
    float4 z = make_float4(0.f, 0.f, 0.f, 0.f);
    for (; i < n4; i += stride) out[i] = z;
}

// W[128][128] fp32 -> W^T[128][128] bf16
__global__ __launch_bounds__(256) void convert_w_kernel(const float* __restrict__ W,
                                                        ushort* __restrict__ wT) {
    int t = blockIdx.x * 256 + threadIdx.x;
    if (t >= D * D) return;
    int r = t >> 7, c = t & 127;
    wT[c * D + r] = f2bf(W[t]);
}

// ---------------- GEMM: support_bf16 = bf16(embeds @ W), via MFMA ----------------

__global__ __launch_bounds__(256) void gemm_mfma(const float* __restrict__ embeds,
                                                 const ushort* __restrict__ wT,
                                                 ushort* __restrict__ support, int N) {
    __shared__ ushort aLds[64 * D];    // 16 KB, XOR-swizzled rows
    __shared__ ushort bLds[D * D];     // 32 KB, XOR-swizzled rows (stores W^T: [n][k])
    const int t = threadIdx.x;
    const int w = t >> 6;        // wave 0..3
    const int l = t & 63;

    // stage W^T (block-invariant): 2048 x 16B chunks
    #pragma unroll
    for (int c = 0; c < 8; ++c) {
        int chunk = c * 256 + t;
        int byteoff = chunk * 16;
        int n = byteoff >> 8;
        int dstoff = byteoff ^ ((n & 7) << 4);
        *(float4*)((char*)bLds + dstoff) = *(const float4*)((const char*)wT + byteoff);
    }

    const int ntiles = (N + 63) >> 6;
    const int kgrp = l >> 4;             // 0..3
    const int lan15 = l & 15;

    for (int tile = blockIdx.x; tile < ntiles; tile += gridDim.x) {
        const int row0 = tile << 6;
        __syncthreads();

        #pragma unroll
        for (int c = 0; c < 4; ++c) {
            int chunk = c * 256 + t;
            int rl = chunk >> 4;
            int cf = (chunk & 15) * 8;
            int grow = row0 + rl;
            short8 v;
            if (grow < N) {
                const float* src = embeds + (size_t)grow * D + cf;
                float4 f0 = *(const float4*)src;
                float4 f1 = *(const float4*)(src + 4);
                v[0] = (short)f2bf(f0.x); v[1] = (short)f2bf(f0.y);
                v[2] = (short)f2bf(f0.z); v[3] = (short)f2bf(f0.w);
                v[4] = (short)f2bf(f1.x); v[5] = (short)f2bf(f1.y);
                v[6] = (short)f2bf(f1.z); v[7] = (short)f2bf(f1.w);
            } else {
                v = (short8)0;
            }
            int byteoff = rl * 256 + cf * 2;
            int dstoff = byteoff ^ ((rl & 7) << 4);
            *(short8*)((char*)aLds + dstoff) = v;
        }
        __syncthreads();

        f32x4 acc[8];
        #pragma unroll
        for (int ct = 0; ct < 8; ++ct) acc[ct] = (f32x4)0.0f;

        const int arow = w * 16 + lan15;
        #pragma unroll
        for (int ks = 0; ks < 4; ++ks) {
            const int kbyte = ks * 64 + kgrp * 16;
            const int aoff = (arow * 256 + kbyte) ^ ((arow & 7) << 4);
            short8 af = *(const short8*)((const char*)aLds + aoff);
            #pragma unroll
            for (int ct = 0; ct < 8; ++ct) {
                const int n = ct * 16 + lan15;
                const int boff = (n * 256 + kbyte) ^ ((n & 7) << 4);
                short8 bfr = *(const short8*)((const char*)bLds + boff);
                acc[ct] = __builtin_amdgcn_mfma_f32_16x16x32_bf16(af, bfr, acc[ct], 0, 0, 0);
            }
        }

        #pragma unroll
        for (int r = 0; r < 4; ++r) {
            const int grow = row0 + w * 16 + kgrp * 4 + r;
            if (grow < N) {
                #pragma unroll
                for (int ct = 0; ct < 8; ++ct) {
                    support[(size_t)grow * D + ct * 16 + lan15] = f2bf(acc[ct][r]);
                }
            }
        }
    }
}

// ---------------- CSR build ----------------

__global__ void hist_kernel(const int* __restrict__ dst, int* __restrict__ cnt, int E) {
    int e = blockIdx.x * blockDim.x + threadIdx.x;
    int stride = gridDim.x * blockDim.x;
    for (; e < E; e += stride) atomicAdd(&cnt[dst[e]], 1);
}

__global__ __launch_bounds__(256) void scan_reduce(const int* __restrict__ cnt,
                                                   int* __restrict__ partials, int N) {
    __shared__ int l[256];
    const int b = blockIdx.x, t = threadIdx.x;
    const int base = b * 1024 + t * 4;
    int s = 0;
    #pragma unroll
    for (int j = 0; j < 4; ++j) {
        int i = base + j;
        s += (i < N) ? cnt[i] : 0;
    }
    l[t] = s;
    __syncthreads();
    for (int off = 128; off > 0; off >>= 1) {
        if (t < off) l[t] += l[t + off];
        __syncthreads();
    }
    if (t == 0) partials[b] = l[0];
}

__global__ __launch_bounds__(128) void scan_partials(int* __restrict__ partials, int nblk) {
    __shared__ int l[128];
    const int t = threadIdx.x;
    const int v = (t < nblk) ? partials[t] : 0;
    l[t] = v;
    __syncthreads();
    for (int off = 1; off < 128; off <<= 1) {
        int x = (t >= off) ? l[t - off] : 0;
        __syncthreads();
        l[t] += x;
        __syncthreads();
    }
    if (t < nblk) partials[t] = l[t] - v;  // exclusive
}

__global__ __launch_bounds__(256) void scan_final(const int* __restrict__ cnt,
                                                  const int* __restrict__ partials,
                                                  int* __restrict__ offsets,
                                                  int* __restrict__ cursor, int N, int E) {
    __shared__ int l[256];
    const int b = blockIdx.x, t = threadIdx.x;
    const int base = b * 1024 + t * 4;
    int v[4];
    int s = 0;
    #pragma unroll
    for (int j = 0; j < 4; ++j) {
        int i = base + j;
        v[j] = (i < N) ? cnt[i] : 0;
        s += v[j];
    }
    l[t] = s;
    __syncthreads();
    for (int off = 1; off < 256; off <<= 1) {
        int x = (t >= off) ? l[t - off] : 0;
        __syncthreads();
        l[t] += x;
        __syncthreads();
    }
    int run = l[t] - s + partials[b];
    #pragma unroll
    for (int j = 0; j < 4; ++j) {
        int i = base + j;
        if (i < N) { offsets[i] = run; cursor[i] = run; }
        run += v[j];
    }
    if (b == 0 && t == 0) offsets[N] = E;
}

// ---------------- two-level fill ----------------

__global__ void init_ccursor(const int* __restrict__ offsets, int* __restrict__ ccursor,
                             int N, int nb) {
    int b = blockIdx.x * blockDim.x + threadIdx.x;
    if (b < nb) ccursor[b] = offsets[min(b * CB, N)];
}

// pass 1: multi-split edges into coarse buckets (contiguous runs per block)
__global__ __launch_bounds__(256) void partition_kernel(const int* __restrict__ dst,
                                                        const int* __restrict__ src,
                                                        const float* __restrict__ vals,
                                                        int* __restrict__ ccursor,
                                                        int2* __restrict__ pay1, int E) {
    __shared__ int hist[NB_MAX];
    __shared__ int base[NB_MAX];
    const int t = threadIdx.x;
    const int ntile = (E + 4095) >> 12;

    for (int tile = blockIdx.x; tile < ntile; tile += gridDim.x) {
        const int e0 = tile << 12;
        if (t < NB_MAX) hist[t] = 0;
        __syncthreads();

        int bk[16], rk[16];
        #pragma unroll
        for (int j = 0; j < 16; ++j) {
            int e = e0 + j * 256 + t;
            bk[j] = -1;
            if (e < E) {
                bk[j] = dst[e] >> 10;
                rk[j] = atomicAdd(&hist[bk[j]], 1);
            }
        }
        __syncthreads();

        if (t < NB_MAX) base[t] = hist[t] ? atomicAdd(&ccursor[t], hist[t]) : 0;
        __syncthreads();

        #pragma unroll
        for (int j = 0; j < 16; ++j) {
            int e = e0 + j * 256 + t;
            if (e >= E) continue;
            int d = dst[e];
            int key = ((d & (CB - 1)) << 17) | src[e];
            pay1[base[bk[j]] + rk[j]] = make_int2(key, __float_as_int(vals[e]));
        }
        __syncthreads();
    }
}

// pass 2: exact placement within each coarse bucket (block-private 50KB window)
__global__ __launch_bounds__(256) void finefill_kernel(const int2* __restrict__ pay1,
                                                       const int* __restrict__ offsets,
                                                       int* __restrict__ cursor,
                                                       int2* __restrict__ pay, int N, int nb) {
    for (int b = blockIdx.x; b < nb; b += gridDim.x) {
        const int beg = offsets[min(b * CB, N)];
        const int end = offsets[min((b + 1) * CB, N)];
        const int d0 = b * CB;
        for (int i = beg + threadIdx.x; i < end; i += 256) {
            int2 p = pay1[i];
            int d = d0 + ((unsigned)p.x >> 17);
            int pos = atomicAdd(&cursor[d], 1);
            pay[pos] = make_int2(p.x & 0x1FFFF, p.y);
        }
    }
}

// legacy single-pass fill (used when N too large for key packing)
__global__ void fill_kernel(const int* __restrict__ dst, const int* __restrict__ src,
                            const float* __restrict__ vals, int* __restrict__ cursor,
                            int2* __restrict__ pay, int E) {
    int e = blockIdx.x * blockDim.x + threadIdx.x;
    int stride = gridDim.x * blockDim.x;
    for (; e < E; e += stride) {
        int d = dst[e];
        int pos = atomicAdd(&cursor[d], 1);
        pay[pos] = make_int2(src[e], __float_as_int(vals[e]));
    }
}

// ---------------- gather-accumulate: one wave per dst node, 4 edges in flight ----------------

__global__ __launch_bounds__(256) void gather_kernel(const ushort* __restrict__ support,
                                                     const int* __restrict__ offsets,
                                                     const int2* __restrict__ pay,
                                                     float* __restrict__ out, int N) {
    const int wid = (blockIdx.x * 256 + threadIdx.x) >> 6;  // wave id = node id
    const int lane = threadIdx.x & 63;
    if (wid >= N) return;

    const int beg = offsets[wid];
    const int end = offsets[wid + 1];
    const int g  = lane >> 4;    // edge slot 0..3
    const int sl = lane & 15;    // column sublane: cols sl*8 .. sl*8+7

    float acc[8];
    #pragma unroll
    for (int j = 0; j < 8; ++j) acc[j] = 0.f;

    for (int i = beg + g; i < end; i += 4) {
        const int2 p = pay[i];
        const float v = __int_as_float(p.y);
        const uint4 m = *(const uint4*)&support[(size_t)p.x * D + sl * 8];  // 8 bf16
        acc[0] += v * __uint_as_float((m.x & 0xFFFFu) << 16);
        acc[1] += v * __uint_as_float(m.x & 0xFFFF0000u);
        acc[2] += v * __uint_as_float((m.y & 0xFFFFu) << 16);
        acc[3] += v * __uint_as_float(m.y & 0xFFFF0000u);
        acc[4] += v * __uint_as_float((m.z & 0xFFFFu) << 16);
        acc[5] += v * __uint_as_float(m.z & 0xFFFF0000u);
        acc[6] += v * __uint_as_float((m.w & 0xFFFFu) << 16);
        acc[7] += v * __uint_as_float(m.w & 0xFFFF0000u);
    }

    #pragma unroll
    for (int j = 0; j < 8; ++j) {
        acc[j] += __shfl_xor(acc[j], 16, 64);
        acc[j] += __shfl_xor(acc[j], 32, 64);
    }

    if (g == 0) {
        float* o = &out[(size_t)wid * D + sl * 8];
        *(float4*)o       = make_float4(acc[0], acc[1], acc[2], acc[3]);
        *(float4*)(o + 4) = make_float4(acc[4], acc[5], acc[6], acc[7]);
    }
}

// ---------------- fallback: atomic scatter (if ws too small) ----------------

__global__ __launch_bounds__(256) void scatter_kernel(const ushort* __restrict__ support,
                                                      const int* __restrict__ dst,
                                                      const int* __restrict__ src,
                                                      const float* __restrict__ vals,
                                                      float* __restrict__ out, int E) {
    const long long tid = (long long)blockIdx.x * blockDim.x + threadIdx.x;
    const int e = (int)(tid >> 6);
    if (e >= E) return;
    const int c = ((int)tid & 63) * 2;

    const int s = src[e];
    const int d = dst[e];
    const float v = vals[e];

    const uint m = *(const uint*)&support[(size_t)s * D + c];
    const float mx = __uint_as_float((m & 0xFFFFu) << 16);
    const float my = __uint_as_float(m & 0xFFFF0000u);
    atomicAdd(&out[(size_t)d * D + c + 0], v * mx);
    atomicAdd(&out[(size_t)d * D + c + 1], v * my);
}

// ---------------- launch ----------------

extern "C" void kernel_launch(void* const* d_in, const int* in_sizes, int n_in,
                              void* d_out, int out_size, void* d_ws, size_t ws_size,
                              hipStream_t stream) {
    const float* embeds = (const float*)d_in[0];
    const float* W      = (const float*)d_in[1];
    const int*   eidx   = (const int*)d_in[2];
    const float* vals   = (const float*)d_in[3];

    const int N = in_sizes[0] / D;   // 100000
    const int E = in_sizes[3];       // 625000
    const int* dstp = eidx;          // edge_index[0]
    const int* srcp = eidx + E;      // edge_index[1]

    float* out = (float*)d_out;

    // workspace layout
    char* p = (char*)d_ws;
    ushort* support = (ushort*)p;      p += (size_t)N * D * 2;    // 25.6 MB bf16
    ushort* wT      = (ushort*)p;      p += (size_t)D * D * 2;    // 32 KB
    int* cnt        = (int*)p;         p += (size_t)N * 4;
    int* offsets    = (int*)p;         p += (size_t)(N + 1) * 4;
    int* cursor     = (int*)p;         p += (size_t)N * 4;
    int* partials   = (int*)p;         p += 2048;
    int* ccursor    = (int*)p;         p += 2048;
    int2* pay       = (int2*)p;        p += (size_t)E * 8;
    int2* pay1      = (int2*)p;        p += (size_t)E * 8;
    const size_t needed = (size_t)(p - (char*)d_ws);
    const size_t needed_legacy = needed - (size_t)E * 8;

    // 1) W -> W^T bf16; support = bf16(embeds @ W)
    convert_w_kernel<<<(D * D + 255) / 256, 256, 0, stream>>>(W, wT);
    gemm_mfma<<<768, 256, 0, stream>>>(embeds, wT, support, N);

    const int nb = (N + CB - 1) / CB;   // 98 coarse buckets
    const bool two_level = (N <= (1 << 17)) && (nb <= NB_MAX) && (ws_size >= needed);

    if (ws_size >= needed_legacy) {
        // --- CSR path: no output atomics ---
        const int nblk = (N + 1023) / 1024;   // 98 (<=128)
        zero_int_kernel<<<128, 256, 0, stream>>>(cnt, N);
        hist_kernel<<<2048, 256, 0, stream>>>(dstp, cnt, E);
        scan_reduce<<<nblk, 256, 0, stream>>>(cnt, partials, N);
        scan_partials<<<1, 128, 0, stream>>>(partials, nblk);
        scan_final<<<nblk, 256, 0, stream>>>(cnt, partials, offsets, cursor, N, E);
        if (two_level) {
            init_ccursor<<<1, NB_MAX, 0, stream>>>(offsets, ccursor, N, nb);
            const int ntile = (E + 4095) / 4096;
            partition_kernel<<<ntile, 256, 0, stream>>>(dstp, srcp, vals, ccursor, pay1, E);
            finefill_kernel<<<nb, 256, 0, stream>>>(pay1, offsets, cursor, pay, N, nb);
        } else {
            fill_kernel<<<2048, 256, 0, stream>>>(dstp, srcp, vals, cursor, pay, E);
        }
        gather_kernel<<<(N + 3) / 4, 256, 0, stream>>>(support, offsets, pay, out, N);
    } else {
        // --- fallback: atomic scatter ---
        zero_f4_kernel<<<2048, 256, 0, stream>>>((float4*)out, out_size / 4);
        const long long nthreads = (long long)E * 64;
        const int blocks = (int)((nthreads + 255) / 256);
        scatter_kernel<<<blocks, 256, 0, stream>>>(support, dstp, srcp, vals, out, E);
    }
}

// Round 6
// 105.378 us; speedup vs baseline: 10.9179x; 1.3654x over previous
//
#include <hip/hip_runtime.h>

#define D 128   // D_IN == D_OUT == 128
#define CB 1024 // nodes per coarse bucket
#define NB_MAX 128

typedef __attribute__((ext_vector_type(8))) short short8;
typedef __attribute__((ext_vector_type(4))) float f32x4;

__device__ inline ushort f2bf(float f) {   // fp32 -> bf16 RNE
    uint u = __float_as_uint(f);
    uint r = (u + 0x7FFFu + ((u >> 16) & 1u)) >> 16;
    return (ushort)r;
}

// ---------------- utility ----------------

__global__ void zero_f4_kernel(float4* __restrict__ out, int n4) {
    int i = blockIdx.x * blockDim.x + threadIdx.x;
    int stride = gridDim.x * blockDim.x;
    float4 z = make_float4(0.f, 0.f, 0.f, 0.f);
    for (; i < n4; i += stride) out[i] = z;
}

// ---------------- GEMM: support_bf16 = bf16(embeds @ W), via MFMA ----------------

__global__ __launch_bounds__(256) void gemm_mfma(const float* __restrict__ embeds,
                                                 const ushort* __restrict__ wT,
                                                 ushort* __restrict__ support, int N) {
    __shared__ ushort aLds[64 * D];    // 16 KB, XOR-swizzled rows
    __shared__ ushort bLds[D * D];     // 32 KB, XOR-swizzled rows (stores W^T: [n][k])
    const int t = threadIdx.x;
    const int w = t >> 6;        // wave 0..3
    const int l = t & 63;

    // stage W^T (block-invariant): 2048 x 16B chunks
    #pragma unroll
    for (int c = 0; c < 8; ++c) {
        int chunk = c * 256 + t;
        int byteoff = chunk * 16;
        int n = byteoff >> 8;
        int dstoff = byteoff ^ ((n & 7) << 4);
        *(float4*)((char*)bLds + dstoff) = *(const float4*)((const char*)wT + byteoff);
    }

    const int ntiles = (N + 63) >> 6;
    const int kgrp = l >> 4;             // 0..3
    const int lan15 = l & 15;

    for (int tile = blockIdx.x; tile < ntiles; tile += gridDim.x) {
        const int row0 = tile << 6;
        __syncthreads();

        #pragma unroll
        for (int c = 0; c < 4; ++c) {
            int chunk = c * 256 + t;
            int rl = chunk >> 4;
            int cf = (chunk & 15) * 8;
            int grow = row0 + rl;
            short8 v;
            if (grow < N) {
                const float* src = embeds + (size_t)grow * D + cf;
                float4 f0 = *(const float4*)src;
                float4 f1 = *(const float4*)(src + 4);
                v[0] = (short)f2bf(f0.x); v[1] = (short)f2bf(f0.y);
                v[2] = (short)f2bf(f0.z); v[3] = (short)f2bf(f0.w);
                v[4] = (short)f2bf(f1.x); v[5] = (short)f2bf(f1.y);
                v[6] = (short)f2bf(f1.z); v[7] = (short)f2bf(f1.w);
            } else {
                v = (short8)0;
            }
            int byteoff = rl * 256 + cf * 2;
            int dstoff = byteoff ^ ((rl & 7) << 4);
            *(short8*)((char*)aLds + dstoff) = v;
        }
        __syncthreads();

        f32x4 acc[8];
        #pragma unroll
        for (int ct = 0; ct < 8; ++ct) acc[ct] = (f32x4)0.0f;

        const int arow = w * 16 + lan15;
        #pragma unroll
        for (int ks = 0; ks < 4; ++ks) {
            const int kbyte = ks * 64 + kgrp * 16;
            const int aoff = (arow * 256 + kbyte) ^ ((arow & 7) << 4);
            short8 af = *(const short8*)((const char*)aLds + aoff);
            #pragma unroll
            for (int ct = 0; ct < 8; ++ct) {
                const int n = ct * 16 + lan15;
                const int boff = (n * 256 + kbyte) ^ ((n & 7) << 4);
                short8 bfr = *(const short8*)((const char*)bLds + boff);
                acc[ct] = __builtin_amdgcn_mfma_f32_16x16x32_bf16(af, bfr, acc[ct], 0, 0, 0);
            }
        }

        #pragma unroll
        for (int r = 0; r < 4; ++r) {
            const int grow = row0 + w * 16 + kgrp * 4 + r;
            if (grow < N) {
                #pragma unroll
                for (int ct = 0; ct < 8; ++ct) {
                    support[(size_t)grow * D + ct * 16 + lan15] = f2bf(acc[ct][r]);
                }
            }
        }
    }
}

// ---------------- coarse histogram (+ fused W^T convert) ----------------

__global__ __launch_bounds__(256) void bucket_hist(const int* __restrict__ dst,
                                                   int* __restrict__ bhist, int E,
                                                   const float* __restrict__ W,
                                                   ushort* __restrict__ wT) {
    __shared__ int h[NB_MAX];
    const int t = threadIdx.x;
    if (t < NB_MAX) h[t] = 0;

    // fused: W[128][128] fp32 -> W^T bf16 (first 64 blocks)
    const int gt = blockIdx.x * 256 + t;
    if (gt < D * D) { int r = gt >> 7, c = gt & 127; wT[c * D + r] = f2bf(W[gt]); }
    __syncthreads();

    int i = gt;
    const int stride = gridDim.x * 256;
    for (; i < E; i += stride) atomicAdd(&h[dst[i] >> 10], 1);
    __syncthreads();
    if (t < NB_MAX && h[t]) atomicAdd(&bhist[t], h[t]);
}

// exclusive scan of nb (<=128) bucket counts; writes cbase[0..nb], ccursor copy
__global__ __launch_bounds__(128) void cscan(const int* __restrict__ bhist,
                                             int* __restrict__ cbase,
                                             int* __restrict__ ccursor, int nb, int E) {
    __shared__ int l[128];
    const int t = threadIdx.x;
    const int v = (t < nb) ? bhist[t] : 0;
    l[t] = v;
    __syncthreads();
    for (int off = 1; off < 128; off <<= 1) {
        int x = (t >= off) ? l[t - off] : 0;
        __syncthreads();
        l[t] += x;
        __syncthreads();
    }
    const int excl = l[t] - v;
    if (t < nb) { cbase[t] = excl; ccursor[t] = excl; }
    if (t == nb - 1) cbase[nb] = excl + v;   // == E
}

// pass 1: multi-split edges into coarse buckets (contiguous runs per block)
__global__ __launch_bounds__(256) void partition_kernel(const int* __restrict__ dst,
                                                        const int* __restrict__ src,
                                                        const float* __restrict__ vals,
                                                        int* __restrict__ ccursor,
                                                        int2* __restrict__ pay1, int E) {
    __shared__ int hist[NB_MAX];
    __shared__ int base[NB_MAX];
    const int t = threadIdx.x;
    const int ntile = (E + 4095) >> 12;

    for (int tile = blockIdx.x; tile < ntile; tile += gridDim.x) {
        const int e0 = tile << 12;
        if (t < NB_MAX) hist[t] = 0;
        __syncthreads();

        int bk[16], rk[16];
        #pragma unroll
        for (int j = 0; j < 16; ++j) {
            int e = e0 + j * 256 + t;
            bk[j] = -1;
            if (e < E) {
                bk[j] = dst[e] >> 10;
                rk[j] = atomicAdd(&hist[bk[j]], 1);
            }
        }
        __syncthreads();

        if (t < NB_MAX) base[t] = hist[t] ? atomicAdd(&ccursor[t], hist[t]) : 0;
        __syncthreads();

        #pragma unroll
        for (int j = 0; j < 16; ++j) {
            int e = e0 + j * 256 + t;
            if (e >= E) continue;
            int d = dst[e];
            int key = ((d & (CB - 1)) << 17) | src[e];
            pay1[base[bk[j]] + rk[j]] = make_int2(key, __float_as_int(vals[e]));
        }
        __syncthreads();
    }
}

// pass 2: per-bucket LDS hist+scan+place; writes per-node offsets AND final payload
__global__ __launch_bounds__(256) void finefill2(const int2* __restrict__ pay1,
                                                 const int* __restrict__ cbase,
                                                 int* __restrict__ offsets,
                                                 int2* __restrict__ pay,
                                                 int N, int nb, int E) {
    __shared__ int lcnt[CB];
    __shared__ int lofs[CB];
    __shared__ int bs[256];
    const int t = threadIdx.x;

    for (int b = blockIdx.x; b < nb; b += gridDim.x) {
        const int beg = cbase[b];
        const int end = cbase[b + 1];
        const int d0 = b * CB;

        #pragma unroll
        for (int j = t; j < CB; j += 256) lcnt[j] = 0;
        __syncthreads();

        for (int i = beg + t; i < end; i += 256)
            atomicAdd(&lcnt[((unsigned)pay1[i].x) >> 17], 1);
        __syncthreads();

        // scan 1024 counts: 4 per thread + block scan
        const int b4 = t * 4;
        const int c0 = lcnt[b4], c1 = lcnt[b4 + 1], c2 = lcnt[b4 + 2], c3 = lcnt[b4 + 3];
        const int s = c0 + c1 + c2 + c3;
        bs[t] = s;
        __syncthreads();
        for (int off = 1; off < 256; off <<= 1) {
            int x = (t >= off) ? bs[t - off] : 0;
            __syncthreads();
            bs[t] += x;
            __syncthreads();
        }
        int run = bs[t] - s + beg;
        lofs[b4] = run; run += c0;
        lofs[b4 + 1] = run; run += c1;
        lofs[b4 + 2] = run; run += c2;
        lofs[b4 + 3] = run;

        #pragma unroll
        for (int j = 0; j < 4; ++j) {
            int d = d0 + b4 + j;
            if (d < N) offsets[d] = lofs[b4 + j];
        }
        __syncthreads();

        // place (lofs doubles as cursor)
        for (int i = beg + t; i < end; i += 256) {
            int2 p = pay1[i];
            int dl = ((unsigned)p.x) >> 17;
            int pos = atomicAdd(&lofs[dl], 1);
            pay[pos] = make_int2(p.x & 0x1FFFF, p.y);
        }
        __syncthreads();
    }
    if (blockIdx.x == 0 && t == 0) offsets[N] = E;
}

// ---------------- gather-accumulate: one wave per dst node, 8 edges in flight ----------------

__global__ __launch_bounds__(256) void gather_kernel(const ushort* __restrict__ support,
                                                     const int* __restrict__ offsets,
                                                     const int2* __restrict__ pay,
                                                     float* __restrict__ out, int N) {
    const int wid = __builtin_amdgcn_readfirstlane((blockIdx.x * 256 + threadIdx.x) >> 6);
    const int lane = threadIdx.x & 63;
    if (wid >= N) return;

    const int beg = offsets[wid];
    const int end = offsets[wid + 1];
    const int g  = lane >> 4;    // edge slot 0..3
    const int sl = lane & 15;    // column sublane: cols sl*8 .. sl*8+7

    float acc[8];
    #pragma unroll
    for (int j = 0; j < 8; ++j) acc[j] = 0.f;

    int i = beg + g;
    for (; i + 4 < end; i += 8) {   // 2 edges per group in flight
        const int2 pA = pay[i];
        const int2 pB = pay[i + 4];
        const float vA = __int_as_float(pA.y);
        const float vB = __int_as_float(pB.y);
        const uint4 mA = *(const uint4*)&support[(size_t)pA.x * D + sl * 8];
        const uint4 mB = *(const uint4*)&support[(size_t)pB.x * D + sl * 8];
        acc[0] += vA * __uint_as_float((mA.x & 0xFFFFu) << 16);
        acc[1] += vA * __uint_as_float(mA.x & 0xFFFF0000u);
        acc[2] += vA * __uint_as_float((mA.y & 0xFFFFu) << 16);
        acc[3] += vA * __uint_as_float(mA.y & 0xFFFF0000u);
        acc[4] += vA * __uint_as_float((mA.z & 0xFFFFu) << 16);
        acc[5] += vA * __uint_as_float(mA.z & 0xFFFF0000u);
        acc[6] += vA * __uint_as_float((mA.w & 0xFFFFu) << 16);
        acc[7] += vA * __uint_as_float(mA.w & 0xFFFF0000u);
        acc[0] += vB * __uint_as_float((mB.x & 0xFFFFu) << 16);
        acc[1] += vB * __uint_as_float(mB.x & 0xFFFF0000u);
        acc[2] += vB * __uint_as_float((mB.y & 0xFFFFu) << 16);
        acc[3] += vB * __uint_as_float(mB.y & 0xFFFF0000u);
        acc[4] += vB * __uint_as_float((mB.z & 0xFFFFu) << 16);
        acc[5] += vB * __uint_as_float(mB.z & 0xFFFF0000u);
        acc[6] += vB * __uint_as_float((mB.w & 0xFFFFu) << 16);
        acc[7] += vB * __uint_as_float(mB.w & 0xFFFF0000u);
    }
    if (i < end) {
        const int2 p = pay[i];
        const float v = __int_as_float(p.y);
        const uint4 m = *(const uint4*)&support[(size_t)p.x * D + sl * 8];
        acc[0] += v * __uint_as_float((m.x & 0xFFFFu) << 16);
        acc[1] += v * __uint_as_float(m.x & 0xFFFF0000u);
        acc[2] += v * __uint_as_float((m.y & 0xFFFFu) << 16);
        acc[3] += v * __uint_as_float(m.y & 0xFFFF0000u);
        acc[4] += v * __uint_as_float((m.z & 0xFFFFu) << 16);
        acc[5] += v * __uint_as_float(m.z & 0xFFFF0000u);
        acc[6] += v * __uint_as_float((m.w & 0xFFFFu) << 16);
        acc[7] += v * __uint_as_float(m.w & 0xFFFF0000u);
    }

    #pragma unroll
    for (int j = 0; j < 8; ++j) {
        acc[j] += __shfl_xor(acc[j], 16, 64);
        acc[j] += __shfl_xor(acc[j], 32, 64);
    }

    if (g == 0) {
        float* o = &out[(size_t)wid * D + sl * 8];
        *(float4*)o       = make_float4(acc[0], acc[1], acc[2], acc[3]);
        *(float4*)(o + 4) = make_float4(acc[4], acc[5], acc[6], acc[7]);
    }
}

// ---------------- fallback: atomic scatter (if path constraints unmet) ----------------

__global__ __launch_bounds__(256) void scatter_kernel(const ushort* __restrict__ support,
                                                      const int* __restrict__ dst,
                                                      const int* __restrict__ src,
                                                      const float* __restrict__ vals,
                                                      float* __restrict__ out, int E) {
    const long long tid = (long long)blockIdx.x * blockDim.x + threadIdx.x;
    const int e = (int)(tid >> 6);
    if (e >= E) return;
    const int c = ((int)tid & 63) * 2;

    const int s = src[e];
    const int d = dst[e];
    const float v = vals[e];

    const uint m = *(const uint*)&support[(size_t)s * D + c];
    const float mx = __uint_as_float((m & 0xFFFFu) << 16);
    const float my = __uint_as_float(m & 0xFFFF0000u);
    atomicAdd(&out[(size_t)d * D + c + 0], v * mx);
    atomicAdd(&out[(size_t)d * D + c + 1], v * my);
}

// ---------------- launch ----------------

static inline char* align256(char* p) {
    return (char*)(((uintptr_t)p + 255) & ~(uintptr_t)255);
}

extern "C" void kernel_launch(void* const* d_in, const int* in_sizes, int n_in,
                              void* d_out, int out_size, void* d_ws, size_t ws_size,
                              hipStream_t stream) {
    const float* embeds = (const float*)d_in[0];
    const float* W      = (const float*)d_in[1];
    const int*   eidx   = (const int*)d_in[2];
    const float* vals   = (const float*)d_in[3];

    const int N = in_sizes[0] / D;   // 100000
    const int E = in_sizes[3];       // 625000
    const int* dstp = eidx;          // edge_index[0]
    const int* srcp = eidx + E;      // edge_index[1]

    float* out = (float*)d_out;

    // workspace layout (256B-aligned chunks)
    char* p = (char*)d_ws;
    ushort* support = (ushort*)p;  p = align256(p + (size_t)N * D * 2);   // 25.6 MB bf16
    ushort* wT      = (ushort*)p;  p = align256(p + (size_t)D * D * 2);   // 32 KB
    int* offsets    = (int*)p;     p = align256(p + (size_t)(N + 1) * 4);
    int* bhist      = (int*)p;     p = align256(p + NB_MAX * 4);
    int* cbase      = (int*)p;     p = align256(p + (NB_MAX + 1) * 4);
    int* ccursor    = (int*)p;     p = align256(p + NB_MAX * 4);
    int2* pay       = (int2*)p;    p = align256(p + (size_t)E * 8);
    int2* pay1      = (int2*)p;    p = align256(p + (size_t)E * 8);
    const size_t needed = (size_t)(p - (char*)d_ws);

    const int nb = (N + CB - 1) / CB;   // 98 coarse buckets
    const bool two_level = (N <= (1 << 17)) && (nb <= NB_MAX) && (ws_size >= needed);

    if (two_level) {
        // CSR build (no per-node global atomics, no output atomics)
        hipMemsetAsync(bhist, 0, NB_MAX * 4, stream);
        bucket_hist<<<256, 256, 0, stream>>>(dstp, bhist, E, W, wT);
        cscan<<<1, 128, 0, stream>>>(bhist, cbase, ccursor, nb, E);

        gemm_mfma<<<768, 256, 0, stream>>>(embeds, wT, support, N);

        const int ntile = (E + 4095) / 4096;
        partition_kernel<<<ntile, 256, 0, stream>>>(dstp, srcp, vals, ccursor, pay1, E);
        finefill2<<<nb, 256, 0, stream>>>(pay1, cbase, offsets, pay, N, nb, E);
        gather_kernel<<<(N + 3) / 4, 256, 0, stream>>>(support, offsets, pay, out, N);
    } else {
        // fallback: convert W inline via bucket_hist's fused path needs bhist; do simple path
        hipMemsetAsync(bhist, 0, NB_MAX * 4, stream);
        bucket_hist<<<256, 256, 0, stream>>>(dstp, bhist, E, W, wT);  // only for wT convert
        gemm_mfma<<<768, 256, 0, stream>>>(embeds, wT, support, N);
        zero_f4_kernel<<<2048, 256, 0, stream>>>((float4*)out, out_size / 4);
        const long long nthreads = (long long)E * 64;
        const int blocks = (int)((nthreads + 255) / 256);
        scatter_kernel<<<blocks, 256, 0, stream>>>(support, dstp, srcp, vals, out, E);
    }
}

// Round 7
// 94.748 us; speedup vs baseline: 12.1429x; 1.1122x over previous
//
#include <hip/hip_runtime.h>

#define D 128       // D_IN == D_OUT == 128
#define CB 256      // nodes per coarse bucket
#define CB_SHIFT 8
#define NB_MAX 512

typedef __attribute__((ext_vector_type(8))) short short8;
typedef __attribute__((ext_vector_type(4))) float f32x4;

__device__ inline ushort f2bf(float f) {   // fp32 -> bf16 RNE
    uint u = __float_as_uint(f);
    uint r = (u + 0x7FFFu + ((u >> 16) & 1u)) >> 16;
    return (ushort)r;
}

// ---------------- utility ----------------

__global__ void zero_f4_kernel(float4* __restrict__ out, int n4) {
    int i = blockIdx.x * blockDim.x + threadIdx.x;
    int stride = gridDim.x * blockDim.x;
    float4 z = make_float4(0.f, 0.f, 0.f, 0.f);
    for (; i < n4; i += stride) out[i] = z;
}

// ---------------- GEMM v2: 512 thr, 128-row tiles, reg-prefetch pipeline ----------------

__global__ __launch_bounds__(512, 4) void gemm_mfma(const float* __restrict__ embeds,
                                                    const ushort* __restrict__ wT,
                                                    ushort* __restrict__ support, int N) {
    __shared__ ushort aLds[128 * D];   // 32 KB, XOR-swizzled rows
    __shared__ ushort bLds[D * D];     // 32 KB, XOR-swizzled rows (W^T: [n][k])
    const int t = threadIdx.x;         // 0..511
    const int w = t >> 6;              // wave 0..7
    const int l = t & 63;
    const int kgrp = l >> 4;           // 0..3
    const int lan15 = l & 15;

    // stage W^T: 2048 x 16B chunks / 512 threads
    #pragma unroll
    for (int c = 0; c < 4; ++c) {
        int chunk = c * 512 + t;
        int byteoff = chunk * 16;
        int n = byteoff >> 8;
        int dstoff = byteoff ^ ((n & 7) << 4);
        *(float4*)((char*)bLds + dstoff) = *(const float4*)((const char*)wT + byteoff);
    }

    const int ntiles = (N + 127) >> 7;
    const int prow = t >> 4;           // base row 0..31 (+ j*32)
    const int pcolf = (t & 15) * 8;    // col in floats

    float4 pf[8];
    int tile = blockIdx.x;
    if (tile < ntiles) {
        #pragma unroll
        for (int j = 0; j < 4; ++j) {
            int grow = (tile << 7) + prow + j * 32;
            if (grow < N) {
                const float* s = embeds + (size_t)grow * D + pcolf;
                pf[2 * j] = *(const float4*)s;
                pf[2 * j + 1] = *(const float4*)(s + 4);
            } else {
                pf[2 * j] = make_float4(0.f, 0.f, 0.f, 0.f);
                pf[2 * j + 1] = make_float4(0.f, 0.f, 0.f, 0.f);
            }
        }
    }

    while (tile < ntiles) {
        const int row0 = tile << 7;
        const int next = tile + gridDim.x;

        __syncthreads();   // previous compute done; aLds reusable (and bLds staged, iter 0)
        #pragma unroll
        for (int j = 0; j < 4; ++j) {
            const int rl = prow + j * 32;
            const float4 f0 = pf[2 * j], f1 = pf[2 * j + 1];
            short8 v;
            v[0] = (short)f2bf(f0.x); v[1] = (short)f2bf(f0.y);
            v[2] = (short)f2bf(f0.z); v[3] = (short)f2bf(f0.w);
            v[4] = (short)f2bf(f1.x); v[5] = (short)f2bf(f1.y);
            v[6] = (short)f2bf(f1.z); v[7] = (short)f2bf(f1.w);
            int byteoff = rl * 256 + pcolf * 2;
            *(short8*)((char*)aLds + (byteoff ^ ((rl & 7) << 4))) = v;
        }
        __syncthreads();

        // prefetch next tile into regs (flies under ds_read + MFMA)
        if (next < ntiles) {
            #pragma unroll
            for (int j = 0; j < 4; ++j) {
                int grow = (next << 7) + prow + j * 32;
                if (grow < N) {
                    const float* s = embeds + (size_t)grow * D + pcolf;
                    pf[2 * j] = *(const float4*)s;
                    pf[2 * j + 1] = *(const float4*)(s + 4);
                } else {
                    pf[2 * j] = make_float4(0.f, 0.f, 0.f, 0.f);
                    pf[2 * j + 1] = make_float4(0.f, 0.f, 0.f, 0.f);
                }
            }
        }

        f32x4 acc[8];
        #pragma unroll
        for (int ct = 0; ct < 8; ++ct) acc[ct] = (f32x4)0.0f;

        const int arow = w * 16 + lan15;
        #pragma unroll
        for (int ks = 0; ks < 4; ++ks) {
            const int kbyte = ks * 64 + kgrp * 16;
            const int aoff = (arow * 256 + kbyte) ^ ((arow & 7) << 4);
            short8 af = *(const short8*)((const char*)aLds + aoff);
            #pragma unroll
            for (int ct = 0; ct < 8; ++ct) {
                const int n = ct * 16 + lan15;
                const int boff = (n * 256 + kbyte) ^ ((n & 7) << 4);
                short8 bfr = *(const short8*)((const char*)bLds + boff);
                acc[ct] = __builtin_amdgcn_mfma_f32_16x16x32_bf16(af, bfr, acc[ct], 0, 0, 0);
            }
        }

        #pragma unroll
        for (int r = 0; r < 4; ++r) {
            const int grow = row0 + w * 16 + kgrp * 4 + r;
            if (grow < N) {
                #pragma unroll
                for (int ct = 0; ct < 8; ++ct) {
                    support[(size_t)grow * D + ct * 16 + lan15] = f2bf(acc[ct][r]);
                }
            }
        }
        tile = next;
    }
}

// ---------------- coarse histogram (+ fused W^T convert) ----------------

__global__ __launch_bounds__(256) void bucket_hist(const int* __restrict__ dst,
                                                   int* __restrict__ bhist, int E,
                                                   const float* __restrict__ W,
                                                   ushort* __restrict__ wT) {
    __shared__ int h[NB_MAX];
    const int t = threadIdx.x;
    #pragma unroll
    for (int j = t; j < NB_MAX; j += 256) h[j] = 0;

    // fused: W[128][128] fp32 -> W^T bf16 (first 64 blocks)
    const int gt = blockIdx.x * 256 + t;
    if (gt < D * D) { int r = gt >> 7, c = gt & 127; wT[c * D + r] = f2bf(W[gt]); }
    __syncthreads();

    const int stride = gridDim.x * 256;
    for (int i = gt; i < E; i += stride) atomicAdd(&h[dst[i] >> CB_SHIFT], 1);
    __syncthreads();
    #pragma unroll
    for (int j = t; j < NB_MAX; j += 256)
        if (h[j]) atomicAdd(&bhist[j], h[j]);
}

// exclusive scan of nb (<=512) bucket counts; writes cbase[0..nb], ccursor copy
__global__ __launch_bounds__(512) void cscan(const int* __restrict__ bhist,
                                             int* __restrict__ cbase,
                                             int* __restrict__ ccursor, int nb, int E) {
    __shared__ int l[512];
    const int t = threadIdx.x;
    const int v = (t < nb) ? bhist[t] : 0;
    l[t] = v;
    __syncthreads();
    for (int off = 1; off < 512; off <<= 1) {
        int x = (t >= off) ? l[t - off] : 0;
        __syncthreads();
        l[t] += x;
        __syncthreads();
    }
    const int excl = l[t] - v;
    if (t < nb) { cbase[t] = excl; ccursor[t] = excl; }
    if (t == nb - 1) cbase[nb] = excl + v;   // == E
}

// pass 1: multi-split edges into coarse buckets (contiguous runs per block-tile)
__global__ __launch_bounds__(256) void partition_kernel(const int* __restrict__ dst,
                                                        const int* __restrict__ src,
                                                        const float* __restrict__ vals,
                                                        int* __restrict__ ccursor,
                                                        int2* __restrict__ pay1, int E) {
    __shared__ int hist[NB_MAX];
    __shared__ int base[NB_MAX];
    const int t = threadIdx.x;
    const int ntile = (E + 4095) >> 12;

    for (int tile = blockIdx.x; tile < ntile; tile += gridDim.x) {
        const int e0 = tile << 12;
        #pragma unroll
        for (int j = t; j < NB_MAX; j += 256) hist[j] = 0;
        __syncthreads();

        int bk[16], rk[16];
        #pragma unroll
        for (int j = 0; j < 16; ++j) {
            int e = e0 + j * 256 + t;
            bk[j] = -1;
            if (e < E) {
                bk[j] = dst[e] >> CB_SHIFT;
                rk[j] = atomicAdd(&hist[bk[j]], 1);
            }
        }
        __syncthreads();

        #pragma unroll
        for (int j = t; j < NB_MAX; j += 256)
            base[j] = hist[j] ? atomicAdd(&ccursor[j], hist[j]) : 0;
        __syncthreads();

        #pragma unroll
        for (int j = 0; j < 16; ++j) {
            int e = e0 + j * 256 + t;
            if (e >= E) continue;
            int d = dst[e];
            int key = ((d & (CB - 1)) << 17) | src[e];
            pay1[base[bk[j]] + rk[j]] = make_int2(key, __float_as_int(vals[e]));
        }
        __syncthreads();
    }
}

// pass 2: per-bucket LDS hist+scan+place; writes per-node offsets AND final payload
__global__ __launch_bounds__(256) void finefill2(const int2* __restrict__ pay1,
                                                 const int* __restrict__ cbase,
                                                 int* __restrict__ offsets,
                                                 int2* __restrict__ pay,
                                                 int N, int nb, int E) {
    __shared__ int lcnt[CB];   // thread t owns node t of the bucket
    __shared__ int bs[CB];
    __shared__ int lofs[CB];
    const int t = threadIdx.x;

    for (int b = blockIdx.x; b < nb; b += gridDim.x) {
        const int beg = cbase[b];
        const int end = cbase[b + 1];
        const int d0 = b << CB_SHIFT;

        lcnt[t] = 0;
        __syncthreads();
        for (int i = beg + t; i < end; i += 256)
            atomicAdd(&lcnt[((unsigned)pay1[i].x) >> 17], 1);
        __syncthreads();

        const int c = lcnt[t];
        bs[t] = c;
        __syncthreads();
        for (int off = 1; off < 256; off <<= 1) {
            int x = (t >= off) ? bs[t - off] : 0;
            __syncthreads();
            bs[t] += x;
            __syncthreads();
        }
        const int run = bs[t] - c + beg;   // exclusive + bucket base
        if (d0 + t < N) offsets[d0 + t] = run;
        lofs[t] = run;
        __syncthreads();

        for (int i = beg + t; i < end; i += 256) {
            int2 p = pay1[i];
            int dl = ((unsigned)p.x) >> 17;
            int pos = atomicAdd(&lofs[dl], 1);
            pay[pos] = make_int2(p.x & 0x1FFFF, p.y);
        }
        __syncthreads();
    }
    if (blockIdx.x == 0 && t == 0) offsets[N] = E;
}

// ---------------- gather: one 16-lane group per dst node, up to 16 rows in flight/wave ----------------

#define EDGE_MAC(P, M)                                          \
    do {                                                        \
        const float v_ = __int_as_float((P).y);                 \
        acc[0] += v_ * __uint_as_float(((M).x & 0xFFFFu) << 16);\
        acc[1] += v_ * __uint_as_float((M).x & 0xFFFF0000u);    \
        acc[2] += v_ * __uint_as_float(((M).y & 0xFFFFu) << 16);\
        acc[3] += v_ * __uint_as_float((M).y & 0xFFFF0000u);    \
        acc[4] += v_ * __uint_as_float(((M).z & 0xFFFFu) << 16);\
        acc[5] += v_ * __uint_as_float((M).z & 0xFFFF0000u);    \
        acc[6] += v_ * __uint_as_float(((M).w & 0xFFFFu) << 16);\
        acc[7] += v_ * __uint_as_float((M).w & 0xFFFF0000u);    \
    } while (0)

__global__ __launch_bounds__(256) void gather_kernel(const ushort* __restrict__ support,
                                                     const int* __restrict__ offsets,
                                                     const int2* __restrict__ pay,
                                                     float* __restrict__ out, int N) {
    const int gid = (blockIdx.x * 256 + threadIdx.x) >> 4;   // group id = node id
    const int sl = threadIdx.x & 15;                         // cols sl*8 .. sl*8+7
    if (gid >= N) return;

    const int beg = offsets[gid];
    const int end = offsets[gid + 1];

    float acc[8];
    #pragma unroll
    for (int j = 0; j < 8; ++j) acc[j] = 0.f;

    int i = beg;
    for (; i + 3 < end; i += 4) {   // 4 edges in flight per group
        const int2 p0 = pay[i], p1 = pay[i + 1], p2 = pay[i + 2], p3 = pay[i + 3];
        const uint4 m0 = *(const uint4*)&support[(size_t)p0.x * D + sl * 8];
        const uint4 m1 = *(const uint4*)&support[(size_t)p1.x * D + sl * 8];
        const uint4 m2 = *(const uint4*)&support[(size_t)p2.x * D + sl * 8];
        const uint4 m3 = *(const uint4*)&support[(size_t)p3.x * D + sl * 8];
        EDGE_MAC(p0, m0); EDGE_MAC(p1, m1); EDGE_MAC(p2, m2); EDGE_MAC(p3, m3);
    }
    for (; i + 1 < end; i += 2) {
        const int2 p0 = pay[i], p1 = pay[i + 1];
        const uint4 m0 = *(const uint4*)&support[(size_t)p0.x * D + sl * 8];
        const uint4 m1 = *(const uint4*)&support[(size_t)p1.x * D + sl * 8];
        EDGE_MAC(p0, m0); EDGE_MAC(p1, m1);
    }
    if (i < end) {
        const int2 p0 = pay[i];
        const uint4 m0 = *(const uint4*)&support[(size_t)p0.x * D + sl * 8];
        EDGE_MAC(p0, m0);
    }

    float* o = &out[(size_t)gid * D + sl * 8];
    *(float4*)o       = make_float4(acc[0], acc[1], acc[2], acc[3]);
    *(float4*)(o + 4) = make_float4(acc[4], acc[5], acc[6], acc[7]);
}

// ---------------- fallback: atomic scatter (if path constraints unmet) ----------------

__global__ __launch_bounds__(256) void scatter_kernel(const ushort* __restrict__ support,
                                                      const int* __restrict__ dst,
                                                      const int* __restrict__ src,
                                                      const float* __restrict__ vals,
                                                      float* __restrict__ out, int E) {
    const long long tid = (long long)blockIdx.x * blockDim.x + threadIdx.x;
    const int e = (int)(tid >> 6);
    if (e >= E) return;
    const int c = ((int)tid & 63) * 2;

    const int s = src[e];
    const int d = dst[e];
    const float v = vals[e];

    const uint m = *(const uint*)&support[(size_t)s * D + c];
    const float mx = __uint_as_float((m & 0xFFFFu) << 16);
    const float my = __uint_as_float(m & 0xFFFF0000u);
    atomicAdd(&out[(size_t)d * D + c + 0], v * mx);
    atomicAdd(&out[(size_t)d * D + c + 1], v * my);
}

// ---------------- launch ----------------

static inline char* align256(char* p) {
    return (char*)(((uintptr_t)p + 255) & ~(uintptr_t)255);
}

extern "C" void kernel_launch(void* const* d_in, const int* in_sizes, int n_in,
                              void* d_out, int out_size, void* d_ws, size_t ws_size,
                              hipStream_t stream) {
    const float* embeds = (const float*)d_in[0];
    const float* W      = (const float*)d_in[1];
    const int*   eidx   = (const int*)d_in[2];
    const float* vals   = (const float*)d_in[3];

    const int N = in_sizes[0] / D;   // 100000
    const int E = in_sizes[3];       // 625000
    const int* dstp = eidx;          // edge_index[0]
    const int* srcp = eidx + E;      // edge_index[1]

    float* out = (float*)d_out;

    // workspace layout (256B-aligned chunks)
    char* p = (char*)d_ws;
    ushort* support = (ushort*)p;  p = align256(p + (size_t)N * D * 2);   // 25.6 MB bf16
    ushort* wT      = (ushort*)p;  p = align256(p + (size_t)D * D * 2);   // 32 KB
    int* offsets    = (int*)p;     p = align256(p + (size_t)(N + 1) * 4);
    int* bhist      = (int*)p;     p = align256(p + NB_MAX * 4);
    int* cbase      = (int*)p;     p = align256(p + (NB_MAX + 1) * 4);
    int* ccursor    = (int*)p;     p = align256(p + NB_MAX * 4);
    int2* pay       = (int2*)p;    p = align256(p + (size_t)E * 8);
    int2* pay1      = (int2*)p;    p = align256(p + (size_t)E * 8);
    const size_t needed = (size_t)(p - (char*)d_ws);

    const int nb = (N + CB - 1) / CB;   // 391 coarse buckets
    const bool two_level = (N <= (1 << 17)) && (nb <= NB_MAX) && (ws_size >= needed);

    if (two_level) {
        hipMemsetAsync(bhist, 0, NB_MAX * 4, stream);
        bucket_hist<<<128, 256, 0, stream>>>(dstp, bhist, E, W, wT);
        cscan<<<1, 512, 0, stream>>>(bhist, cbase, ccursor, nb, E);

        gemm_mfma<<<512, 512, 0, stream>>>(embeds, wT, support, N);

        const int ntile = (E + 4095) / 4096;
        partition_kernel<<<ntile, 256, 0, stream>>>(dstp, srcp, vals, ccursor, pay1, E);
        finefill2<<<nb, 256, 0, stream>>>(pay1, cbase, offsets, pay, N, nb, E);
        gather_kernel<<<(N * 16 + 255) / 256, 256, 0, stream>>>(support, offsets, pay, out, N);
    } else {
        hipMemsetAsync(bhist, 0, NB_MAX * 4, stream);
        bucket_hist<<<128, 256, 0, stream>>>(dstp, bhist, E, W, wT);  // for wT convert
        gemm_mfma<<<512, 512, 0, stream>>>(embeds, wT, support, N);
        zero_f4_kernel<<<2048, 256, 0, stream>>>((float4*)out, out_size / 4);
        const long long nthreads = (long long)E * 64;
        const int blocks = (int)((nthreads + 255) / 256);
        scatter_kernel<<<blocks, 256, 0, stream>>>(support, dstp, srcp, vals, out, E);
    }
}